// Round 11
// baseline (301.181 us; speedup 1.0000x reference)
//
#include <hip/hip_runtime.h>
#include <float.h>
#include <math.h>

#define Bc 512
#define Sc 100
#define Hc 1024
#define Ac 128
#define Nc 8

// ---------------- K0a: positional-encoding table pe[S][H] ----------------
__global__ __launch_bounds__(256) void pe_kernel(float* __restrict__ pe){
  int s = blockIdx.x;
  int t = threadIdx.x;
  const float fac = (float)(-9.210340371976184 / 1024.0);  // -ln(10000)/H
  for(int i = t; i < Hc/2; i += 256){
    float div = expf((float)(2*i) * fac);
    float a = (float)s * div;
    pe[s*Hc + 2*i]     = sinf(a);
    pe[s*Hc + 2*i + 1] = cosf(a);
  }
}

// ---------------- K0b: pesum[h] = sum_s pe[s][h] ----------------
__global__ __launch_bounds__(256) void pesum_kernel(const float* __restrict__ pe, float* __restrict__ pesum){
  int h = blockIdx.x*256 + threadIdx.x;
  float acc = 0.f;
  for(int s = 0; s < Sc; ++s) acc += pe[s*Hc + h];
  pesum[h] = acc;
}

// ---------------- K1: xsp[b][q][h] = sum_{s in quarter q} x[b,s,h]  (+pesum at q==0) ----------------
// 2048 blocks = 8/CU (proven best xsum config).
__global__ __launch_bounds__(256) void xsum_kernel(const float* __restrict__ x, const float* __restrict__ pesum,
                                                   float* __restrict__ xsp){
  int b = blockIdx.x;
  int q = blockIdx.y;
  int t = threadIdx.x;
  const float4* xr = (const float4*)(x + (size_t)b*Sc*Hc);
  float4 acc;
  if(q == 0) acc = ((const float4*)pesum)[t];
  else       acc = make_float4(0.f,0.f,0.f,0.f);
  int s0 = q*25;
  #pragma unroll 5
  for(int s = s0; s < s0+25; ++s){
    float4 v = xr[s*(Hc/4) + t];
    acc.x += v.x; acc.y += v.y; acc.z += v.z; acc.w += v.w;
  }
  ((float4*)(xsp + ((size_t)b*4 + q)*Hc))[t] = acc;
}

// ---------------- K2: Ksum8[ks][b][j] = sum_{k in slice ks(128)} xs[b][k] * Wk[j][k] ----------------
// A (xs 64x128, quarter-summed from xsp) staged ONCE in LDS [m][k]; B = Wk read from
// GLOBAL k-major per thread (8 j-rows, float4 along k, L1-resident 64KB slice).
// Inner loop: 4 LDS b128 + 8 global b128 per 4 kk for 128 FMA -> VALU-bound, 0 barriers.
__global__ __launch_bounds__(256) void ksum_gemm3(const float* __restrict__ xsp, const float* __restrict__ Wk,
                                                  float* __restrict__ Ksum8){
  __shared__ float As[64*132];         // [m][k] pad 132 (33 KB)
  const int t = threadIdx.x;
  const int j0 = blockIdx.x*128, b0 = blockIdx.y*64, kb = blockIdx.z*128;
  const int ty = (t>>4), tx = t&15;    // ty 0..15 -> m-group; tx -> j-group

  // stage A once: thread t covers m = t>>2, kc = (t&3)*8 + i  (8 float4 along k)
  {
    int m = t>>2;
    const float* xa = xsp + (size_t)(b0+m)*(4*Hc) + kb;
    #pragma unroll 8
    for(int i = 0; i < 8; ++i){
      int kc = (t&3)*8 + i;
      float4 s0 = *(const float4*)(xa + kc*4);
      float4 s1 = *(const float4*)(xa + Hc   + kc*4);
      float4 s2 = *(const float4*)(xa + 2*Hc + kc*4);
      float4 s3 = *(const float4*)(xa + 3*Hc + kc*4);
      s0.x += s1.x + s2.x + s3.x;
      s0.y += s1.y + s2.y + s3.y;
      s0.z += s1.z + s2.z + s3.z;
      s0.w += s1.w + s2.w + s3.w;
      *(float4*)&As[m*132 + kc*4] = s0;
    }
  }
  __syncthreads();

  // B row pointers (8 j-rows per thread)
  const float* Bp[8];
  #pragma unroll
  for(int jj = 0; jj < 8; ++jj){
    int j = (jj < 4) ? (tx*4 + jj) : (64 + tx*4 + (jj-4));
    Bp[jj] = Wk + (size_t)(j0 + j)*Hc + kb;
  }

  float acc[4][8];
  #pragma unroll
  for(int i = 0; i < 4; ++i)
    #pragma unroll
    for(int j = 0; j < 8; ++j) acc[i][j] = 0.f;

  #pragma unroll 4
  for(int kc = 0; kc < 32; ++kc){      // 4 k per iter
    float4 a[4], bv[8];
    #pragma unroll
    for(int i = 0; i < 4; ++i)
      a[i] = *(const float4*)&As[(ty*4+i)*132 + kc*4];
    #pragma unroll
    for(int jj = 0; jj < 8; ++jj)
      bv[jj] = *(const float4*)(Bp[jj] + kc*4);
    #pragma unroll
    for(int i = 0; i < 4; ++i)
      #pragma unroll
      for(int jj = 0; jj < 8; ++jj){
        acc[i][jj] = fmaf(a[i].x, bv[jj].x, acc[i][jj]);
        acc[i][jj] = fmaf(a[i].y, bv[jj].y, acc[i][jj]);
        acc[i][jj] = fmaf(a[i].z, bv[jj].z, acc[i][jj]);
        acc[i][jj] = fmaf(a[i].w, bv[jj].w, acc[i][jj]);
      }
  }

  #pragma unroll
  for(int i = 0; i < 4; ++i){
    float* cp = Ksum8 + (((size_t)blockIdx.z*Bc + b0 + ty*4 + i)<<10) + j0 + tx*4;
    *(float4*)cp        = make_float4(acc[i][0],acc[i][1],acc[i][2],acc[i][3]);
    *(float4*)(cp + 64) = make_float4(acc[i][4],acc[i][5],acc[i][6],acc[i][7]);
  }
}

// ---------------- K3: v[b][n][h] = sum_a (sum_ks Ksum8[ks][b][nA+a]) * Wq[nA+a][h] ----------------
// A (64x128, 8-slice-summed) staged once in LDS [k][m]; B = Wq read from GLOBAL per kk
// (j-contiguous 256B per wave-instr, L1-resident). 1 LDS b128 + 2 global b128 per kk.
__global__ __launch_bounds__(256) void v_gemm3(const float* __restrict__ Ksum8, const float* __restrict__ Wq,
                                               float* __restrict__ v){
  __shared__ float As2[128*68];        // [k][m] pad 68 (34.8 KB)
  const int t = threadIdx.x;
  const int h0 = blockIdx.x*128, b0 = blockIdx.y*64, n = blockIdx.z;
  const int ty = (t>>4), tx = t&15;
  const size_t sl = (size_t)Bc*Hc;

  // stage A once: thread t covers m = t>>2, ac = (t&3)*8 + i (8 float4 along a), 8 slices summed
  {
    int m = t>>2;
    const float* ka = Ksum8 + ((size_t)(b0+m)<<10) + n*Ac;
    #pragma unroll 8
    for(int i = 0; i < 8; ++i){
      int ac = (t&3)*8 + i;
      float4 s = *(const float4*)(ka + ac*4);
      #pragma unroll
      for(int ks = 1; ks < 8; ++ks){
        float4 q = *(const float4*)(ka + ks*sl + ac*4);
        s.x += q.x; s.y += q.y; s.z += q.z; s.w += q.w;
      }
      As2[(ac*4+0)*68 + m] = s.x;
      As2[(ac*4+1)*68 + m] = s.y;
      As2[(ac*4+2)*68 + m] = s.z;
      As2[(ac*4+3)*68 + m] = s.w;
    }
  }
  __syncthreads();

  float acc[4][8];
  #pragma unroll
  for(int i = 0; i < 4; ++i)
    #pragma unroll
    for(int j = 0; j < 8; ++j) acc[i][j] = 0.f;

  const float* wb = Wq + ((size_t)n*Ac<<10) + h0;
  #pragma unroll 4
  for(int kk = 0; kk < Ac; ++kk){
    float4 a4 = *(const float4*)&As2[kk*68 + ty*4];      // 4 m, broadcast across tx
    float4 bu = *(const float4*)(wb + ((size_t)kk<<10) + tx*4);
    float4 bw = *(const float4*)(wb + ((size_t)kk<<10) + 64 + tx*4);
    float am[4] = {a4.x, a4.y, a4.z, a4.w};
    #pragma unroll
    for(int i = 0; i < 4; ++i){
      acc[i][0] = fmaf(am[i], bu.x, acc[i][0]);
      acc[i][1] = fmaf(am[i], bu.y, acc[i][1]);
      acc[i][2] = fmaf(am[i], bu.z, acc[i][2]);
      acc[i][3] = fmaf(am[i], bu.w, acc[i][3]);
      acc[i][4] = fmaf(am[i], bw.x, acc[i][4]);
      acc[i][5] = fmaf(am[i], bw.y, acc[i][5]);
      acc[i][6] = fmaf(am[i], bw.z, acc[i][6]);
      acc[i][7] = fmaf(am[i], bw.w, acc[i][7]);
    }
  }

  #pragma unroll
  for(int i = 0; i < 4; ++i){
    float* cp = v + (((size_t)(b0 + ty*4 + i)*Nc + n)<<10) + h0 + tx*4;
    *(float4*)cp        = make_float4(acc[i][0],acc[i][1],acc[i][2],acc[i][3]);
    *(float4*)(cp + 64) = make_float4(acc[i][4],acc[i][5],acc[i][6],acc[i][7]);
  }
}

// ---------------- K4: x.v logits -> +gumbel -> argmax_s -> gather rows of x ----------------
// Round-4 attn (best proven).
__global__ __launch_bounds__(1024) void attn_kernel(const float* __restrict__ x, const float* __restrict__ pe,
                                                    const float* __restrict__ v, const float* __restrict__ g,
                                                    float* __restrict__ out){
  __shared__ float4 tile[1600];        // [r<100][16 slots], 16B-slot XOR swizzle, 25.6 KB
  __shared__ float part[8][Nc][104];   // [kq][n][s] 26.6 KB
  __shared__ int sidx[Nc];
  const int b = blockIdx.x;
  const int t = threadIdx.x;
  const int lane = t & 63;
  const int w  = __builtin_amdgcn_readfirstlane(t >> 6);  // wave id 0..15
  const int kq = w & 7, sh = w >> 3;

  const int r1 = t >> 4, c1 = t & 15;
  const bool has2 = (t < 576);
  const int e2 = t + 1024;
  const int r2 = e2 >> 4, c2 = e2 & 15;

  const float* xb = x + (size_t)b*Sc*Hc;
  const float* vb = v + (size_t)b*Nc*Hc;

  int rw = sh*64 + lane;               // 0..127
  int r  = (rw < Sc) ? rw : (Sc-1);
  const bool valid = (rw < Sc);

  float acc[Nc];
  #pragma unroll
  for(int n = 0; n < Nc; ++n) acc[n] = 0.f;

  float4 xv1 = *(const float4*)(xb + r1*Hc + c1*4);
  float4 pv1 = *(const float4*)(pe + r1*Hc + c1*4);
  float4 xv2 = make_float4(0,0,0,0), pv2 = make_float4(0,0,0,0);
  if(has2){ xv2 = *(const float4*)(xb + r2*Hc + c2*4);
            pv2 = *(const float4*)(pe + r2*Hc + c2*4); }

  for(int kt = 0; kt < 16; ++kt){
    __syncthreads();
    tile[r1*16 + (c1 ^ (r1&7))] = make_float4(xv1.x+pv1.x, xv1.y+pv1.y, xv1.z+pv1.z, xv1.w+pv1.w);
    if(has2)
      tile[r2*16 + (c2 ^ (r2&7))] = make_float4(xv2.x+pv2.x, xv2.y+pv2.y, xv2.z+pv2.z, xv2.w+pv2.w);
    if(kt < 15){
      int ko = (kt+1)*64;
      xv1 = *(const float4*)(xb + r1*Hc + ko + c1*4);
      pv1 = *(const float4*)(pe + r1*Hc + ko + c1*4);
      if(has2){ xv2 = *(const float4*)(xb + r2*Hc + ko + c2*4);
                pv2 = *(const float4*)(pe + r2*Hc + ko + c2*4); }
    }
    __syncthreads();
    #pragma unroll
    for(int j = 0; j < 2; ++j){
      float4 xe = tile[r*16 + ((kq*2 + j) ^ (r&7))];
      const float* vk = vb + kt*64 + kq*8 + j*4;
      #pragma unroll
      for(int n = 0; n < Nc; ++n){
        const float* vn = vk + n*Hc;
        acc[n] = fmaf(xe.x, vn[0], acc[n]);
        acc[n] = fmaf(xe.y, vn[1], acc[n]);
        acc[n] = fmaf(xe.z, vn[2], acc[n]);
        acc[n] = fmaf(xe.w, vn[3], acc[n]);
      }
    }
  }
  if(valid){
    #pragma unroll
    for(int n = 0; n < Nc; ++n) part[kq][n][rw] = acc[n];
  }
  __syncthreads();

  if(w < Nc){
    int n = w, j = lane;
    float best = -FLT_MAX; int bidx = 0;
    #pragma unroll
    for(int i = 0; i < 2; ++i){
      int s2 = j + 64*i;
      if(s2 < Sc){
        float dot = 0.f;
        #pragma unroll
        for(int q = 0; q < 8; ++q) dot += part[q][n][s2];
        float y = dot/3200.0f + g[(size_t)(b*Nc + n)*Sc + s2];
        if(y > best){ best = y; bidx = s2; }   // strict > keeps first index (jnp tie rule)
      }
    }
    #pragma unroll
    for(int m = 32; m >= 1; m >>= 1){
      float ob = __shfl_xor(best, m, 64);
      int   oi = __shfl_xor(bidx, m, 64);
      if(ob > best || (ob == best && oi < bidx)){ best = ob; bidx = oi; }
    }
    if(j == 0) sidx[n] = bidx;
  }
  __syncthreads();

  const float4* xb4 = (const float4*)xb;
  float4* ob4 = (float4*)(out + (size_t)b*Nc*Hc);
  #pragma unroll
  for(int i = 0; i < 2; ++i){
    int idx = i*1024 + t;
    int nn = idx >> 8, c = idx & 255;
    ob4[idx] = xb4[sidx[nn]*256 + c];
  }
}

extern "C" void kernel_launch(void* const* d_in, const int* in_sizes, int n_in,
                              void* d_out, int out_size, void* d_ws, size_t ws_size,
                              hipStream_t stream) {
  const float* x  = (const float*)d_in[0];   // [512,100,1024]
  const float* Wq = (const float*)d_in[1];   // [1024,1024]
  const float* Wk = (const float*)d_in[2];   // [1024,1024]
  const float* g  = (const float*)d_in[3];   // [4096,100]
  float* out = (float*)d_out;                // [512,8,1024]

  char* ws = (char*)d_ws;
  float* pe    = (float*)(ws);                //    409,600 B
  float* pesum = (float*)(ws +    409600);    //      4,096 B
  float* xsp   = (float*)(ws +    413696);    //  8,388,608 B  [512][4][1024]
  float* Ksum8 = (float*)(ws +   8802304);    // 16,777,216 B  [8][512][1024]
  float* v     = (float*)(ws +  25579520);    // 16,777,216 B  (total ~42.4 MB)

  pe_kernel   <<<100, 256, 0, stream>>>(pe);
  pesum_kernel<<<4,   256, 0, stream>>>(pe, pesum);
  xsum_kernel <<<dim3(512,4), 256, 0, stream>>>(x, pesum, xsp);
  ksum_gemm3  <<<dim3(8,8,8), 256, 0, stream>>>(xsp, Wk, Ksum8);
  v_gemm3     <<<dim3(8,8,8), 256, 0, stream>>>(Ksum8, Wq, v);
  attn_kernel <<<512, 1024, 0, stream>>>(x, pe, v, g, out);
}

// Round 12
// 145.377 us; speedup vs baseline: 2.0717x; 2.0717x over previous
//
#include <hip/hip_runtime.h>
#include <float.h>
#include <math.h>

#define Bc 512
#define Sc 100
#define Hc 1024
#define Ac 128
#define Nc 8
#define PDST 196   // [k][*] tile row stride: 16 blocks x (8 data + 4 pad) + 4 (rows offset by 4 banks)

// ---------------- K0a: positional-encoding table pe[S][H] ----------------
__global__ __launch_bounds__(256) void pe_kernel(float* __restrict__ pe){
  int s = blockIdx.x;
  int t = threadIdx.x;
  const float fac = (float)(-9.210340371976184 / 1024.0);  // -ln(10000)/H
  for(int i = t; i < Hc/2; i += 256){
    float div = expf((float)(2*i) * fac);
    float a = (float)s * div;
    pe[s*Hc + 2*i]     = sinf(a);
    pe[s*Hc + 2*i + 1] = cosf(a);
  }
}

// ---------------- K0b: pesum[h] = sum_s pe[s][h] ----------------
__global__ __launch_bounds__(256) void pesum_kernel(const float* __restrict__ pe, float* __restrict__ pesum){
  int h = blockIdx.x*256 + threadIdx.x;
  float acc = 0.f;
  for(int s = 0; s < Sc; ++s) acc += pe[s*Hc + h];
  pesum[h] = acc;
}

// ---------------- K1: xsp[b][q][h] = sum_{s in quarter q} x[b,s,h]  (+pesum at q==0) ----------------
__global__ __launch_bounds__(256) void xsum_kernel(const float* __restrict__ x, const float* __restrict__ pesum,
                                                   float* __restrict__ xsp){
  int b = blockIdx.x;
  int q = blockIdx.y;
  int t = threadIdx.x;
  const float4* xr = (const float4*)(x + (size_t)b*Sc*Hc);
  float4 acc;
  if(q == 0) acc = ((const float4*)pesum)[t];
  else       acc = make_float4(0.f,0.f,0.f,0.f);
  int s0 = q*25;
  #pragma unroll 5
  for(int s = s0; s < s0+25; ++s){
    float4 v = xr[s*(Hc/4) + t];
    acc.x += v.x; acc.y += v.y; acc.z += v.z; acc.w += v.w;
  }
  ((float4*)(xsp + ((size_t)b*4 + q)*Hc))[t] = acc;
}

// ---------------- K1b: xs[b][h] = sum_q xsp[b][q][h] ----------------
__global__ __launch_bounds__(256) void xsred_kernel(const float* __restrict__ xsp, float* __restrict__ xs){
  int b = blockIdx.x, t = threadIdx.x;
  const float4* p = (const float4*)(xsp + (size_t)b*4*Hc);
  float4 a = p[t], b1 = p[256+t], c = p[512+t], d = p[768+t];
  a.x += b1.x + c.x + d.x;
  a.y += b1.y + c.y + d.y;
  a.z += b1.z + c.z + d.z;
  a.w += b1.w + c.w + d.w;
  ((float4*)(xs + (size_t)b*Hc))[t] = a;
}

// ---------------- K2: Ksum8[ks][b][j] = sum_{k in slice ks(128)} xs[b][k] * Wk[j][k] ----------------
// 128x128 tile, 8x8 fragment, 256 thr. LDS [k][row-blocks-of-8, stride 12] pad ->
// fragment reads <=2-way bank-aliased (free). Reg-prefetch pipelining across 4 chunks.
__global__ __launch_bounds__(256) void ksum_gemm4(const float* __restrict__ xs, const float* __restrict__ Wk,
                                                  float* __restrict__ Ksum8){
  __shared__ float As[32*PDST];   // [k][m] 25.1 KB
  __shared__ float Bs[32*PDST];   // [k][j] 25.1 KB
  const int t = threadIdx.x;
  const int j0 = blockIdx.x*128, b0 = blockIdx.y*128, kb = blockIdx.z*128;
  const int ty = t>>4, tx = t&15;
  const int lr = t>>1, lh = t&1;                 // staging: row 0..127, k-half
  const int pj = (lr>>3)*12 + (lr&7);            // physical col of row lr

  float acc[8][8];
  #pragma unroll
  for(int i = 0; i < 8; ++i)
    #pragma unroll
    for(int j = 0; j < 8; ++j) acc[i][j] = 0.f;

  const float* xa = xs + (size_t)(b0+lr)*Hc + kb + lh*16;
  const float* wa = Wk + (size_t)(j0+lr)*Hc + kb + lh*16;
  float4 a4[4], b4[4], a4n[4], b4n[4];
  #pragma unroll
  for(int i = 0; i < 4; ++i){ a4[i] = *(const float4*)(xa + i*4);
                              b4[i] = *(const float4*)(wa + i*4); }

  for(int c0 = 0; c0 < 4; ++c0){
    __syncthreads();                             // previous chunk's LDS reads complete
    #pragma unroll
    for(int i = 0; i < 4; ++i){
      int k = lh*16 + i*4;
      As[(k+0)*PDST + pj] = a4[i].x; As[(k+1)*PDST + pj] = a4[i].y;
      As[(k+2)*PDST + pj] = a4[i].z; As[(k+3)*PDST + pj] = a4[i].w;
      Bs[(k+0)*PDST + pj] = b4[i].x; Bs[(k+1)*PDST + pj] = b4[i].y;
      Bs[(k+2)*PDST + pj] = b4[i].z; Bs[(k+3)*PDST + pj] = b4[i].w;
    }
    if(c0 < 3){                                  // prefetch next chunk into regs
      #pragma unroll
      for(int i = 0; i < 4; ++i){
        a4n[i] = *(const float4*)(xa + (c0+1)*32 + i*4);
        b4n[i] = *(const float4*)(wa + (c0+1)*32 + i*4);
      }
    }
    __syncthreads();                             // chunk staged
    #pragma unroll 4
    for(int kk = 0; kk < 32; ++kk){
      const float* ar = &As[kk*PDST + ty*12];
      const float* br = &Bs[kk*PDST + tx*12];
      float4 au = *(const float4*)(ar),   av = *(const float4*)(ar + 4);
      float4 bu = *(const float4*)(br),   bv = *(const float4*)(br + 4);
      float am[8] = {au.x,au.y,au.z,au.w, av.x,av.y,av.z,av.w};
      float bn[8] = {bu.x,bu.y,bu.z,bu.w, bv.x,bv.y,bv.z,bv.w};
      #pragma unroll
      for(int i = 0; i < 8; ++i)
        #pragma unroll
        for(int j = 0; j < 8; ++j)
          acc[i][j] = fmaf(am[i], bn[j], acc[i][j]);
    }
    a4[0]=a4n[0]; a4[1]=a4n[1]; a4[2]=a4n[2]; a4[3]=a4n[3];
    b4[0]=b4n[0]; b4[1]=b4n[1]; b4[2]=b4n[2]; b4[3]=b4n[3];
  }

  #pragma unroll
  for(int i = 0; i < 8; ++i){
    float* cp = Ksum8 + (((size_t)blockIdx.z*Bc + b0 + ty*8 + i)<<10) + j0 + tx*8;
    *(float4*)cp     = make_float4(acc[i][0],acc[i][1],acc[i][2],acc[i][3]);
    *(float4*)(cp+4) = make_float4(acc[i][4],acc[i][5],acc[i][6],acc[i][7]);
  }
}

// ---------------- K2b: Ksum[b][j] = sum_ks Ksum8[ks][b][j] ----------------
__global__ __launch_bounds__(256) void ksred8_kernel(const float* __restrict__ Ksum8, float* __restrict__ Ksum){
  int b = blockIdx.x, t = threadIdx.x;
  const float4* p = (const float4*)(Ksum8 + ((size_t)b<<10));
  const size_t sl = (size_t)Bc*Hc/4;
  float4 a = p[t];
  #pragma unroll
  for(int i = 1; i < 8; ++i){
    float4 q = p[i*sl + t];
    a.x += q.x; a.y += q.y; a.z += q.z; a.w += q.w;
  }
  ((float4*)(Ksum + ((size_t)b<<10)))[t] = a;
}

// ---------------- K3: v[b][n][h] = sum_a Ksum[b][n*A+a] * Wq[n*A+a][h] ----------------
// Same 128x128 / 8x8 structure; Wq already [a][h] so B stages with direct b128 writes.
__global__ __launch_bounds__(256) void v_gemm4(const float* __restrict__ Ksum, const float* __restrict__ Wq,
                                               float* __restrict__ v){
  __shared__ float As[32*PDST];   // [a][b-rows]
  __shared__ float Bs[32*PDST];   // [a][h]
  const int t = threadIdx.x;
  const int h0 = blockIdx.x*128, b0 = blockIdx.y*128, n = blockIdx.z;
  const int ty = t>>4, tx = t&15;
  const int lr = t>>1, lh = t&1;                 // A staging
  const int pj = (lr>>3)*12 + (lr&7);
  const int rr = t>>3, cc = t&7;                 // B staging: a-row 0..31, h-chunk

  float acc[8][8];
  #pragma unroll
  for(int i = 0; i < 8; ++i)
    #pragma unroll
    for(int j = 0; j < 8; ++j) acc[i][j] = 0.f;

  const float* ka = Ksum + (size_t)(b0+lr)*Hc + n*Ac + lh*16;
  float4 a4[4], b4[4], a4n[4], b4n[4];
  #pragma unroll
  for(int i = 0; i < 4; ++i){
    a4[i] = *(const float4*)(ka + i*4);
    b4[i] = *(const float4*)(Wq + (size_t)(n*Ac + rr)*Hc + h0 + cc*16 + i*4);
  }

  for(int c0 = 0; c0 < 4; ++c0){
    __syncthreads();
    #pragma unroll
    for(int i = 0; i < 4; ++i){
      int k = lh*16 + i*4;
      As[(k+0)*PDST + pj] = a4[i].x; As[(k+1)*PDST + pj] = a4[i].y;
      As[(k+2)*PDST + pj] = a4[i].z; As[(k+3)*PDST + pj] = a4[i].w;
      int h = cc*16 + i*4;
      *(float4*)&Bs[rr*PDST + (h>>3)*12 + (h&7)] = b4[i];
    }
    if(c0 < 3){
      #pragma unroll
      for(int i = 0; i < 4; ++i){
        a4n[i] = *(const float4*)(ka + (c0+1)*32 + i*4);
        b4n[i] = *(const float4*)(Wq + (size_t)(n*Ac + (c0+1)*32 + rr)*Hc + h0 + cc*16 + i*4);
      }
    }
    __syncthreads();
    #pragma unroll 4
    for(int kk = 0; kk < 32; ++kk){
      const float* ar = &As[kk*PDST + ty*12];
      const float* br = &Bs[kk*PDST + tx*12];
      float4 au = *(const float4*)(ar),   av = *(const float4*)(ar + 4);
      float4 bu = *(const float4*)(br),   bv = *(const float4*)(br + 4);
      float am[8] = {au.x,au.y,au.z,au.w, av.x,av.y,av.z,av.w};
      float bn[8] = {bu.x,bu.y,bu.z,bu.w, bv.x,bv.y,bv.z,bv.w};
      #pragma unroll
      for(int i = 0; i < 8; ++i)
        #pragma unroll
        for(int j = 0; j < 8; ++j)
          acc[i][j] = fmaf(am[i], bn[j], acc[i][j]);
    }
    a4[0]=a4n[0]; a4[1]=a4n[1]; a4[2]=a4n[2]; a4[3]=a4n[3];
    b4[0]=b4n[0]; b4[1]=b4n[1]; b4[2]=b4n[2]; b4[3]=b4n[3];
  }

  #pragma unroll
  for(int i = 0; i < 8; ++i){
    float* cp = v + (((size_t)(b0 + ty*8 + i)*Nc + n)<<10) + h0 + tx*8;
    *(float4*)cp     = make_float4(acc[i][0],acc[i][1],acc[i][2],acc[i][3]);
    *(float4*)(cp+4) = make_float4(acc[i][4],acc[i][5],acc[i][6],acc[i][7]);
  }
}

// ---------------- K4: x.v logits -> +gumbel -> argmax_s -> gather rows of x ----------------
// Round-4 attn (best proven).
__global__ __launch_bounds__(1024) void attn_kernel(const float* __restrict__ x, const float* __restrict__ pe,
                                                    const float* __restrict__ v, const float* __restrict__ g,
                                                    float* __restrict__ out){
  __shared__ float4 tile[1600];        // [r<100][16 slots], 16B-slot XOR swizzle, 25.6 KB
  __shared__ float part[8][Nc][104];   // [kq][n][s] 26.6 KB
  __shared__ int sidx[Nc];
  const int b = blockIdx.x;
  const int t = threadIdx.x;
  const int lane = t & 63;
  const int w  = __builtin_amdgcn_readfirstlane(t >> 6);  // wave id 0..15
  const int kq = w & 7, sh = w >> 3;

  const int r1 = t >> 4, c1 = t & 15;
  const bool has2 = (t < 576);
  const int e2 = t + 1024;
  const int r2 = e2 >> 4, c2 = e2 & 15;

  const float* xb = x + (size_t)b*Sc*Hc;
  const float* vb = v + (size_t)b*Nc*Hc;

  int rw = sh*64 + lane;               // 0..127
  int r  = (rw < Sc) ? rw : (Sc-1);
  const bool valid = (rw < Sc);

  float acc[Nc];
  #pragma unroll
  for(int n = 0; n < Nc; ++n) acc[n] = 0.f;

  float4 xv1 = *(const float4*)(xb + r1*Hc + c1*4);
  float4 pv1 = *(const float4*)(pe + r1*Hc + c1*4);
  float4 xv2 = make_float4(0,0,0,0), pv2 = make_float4(0,0,0,0);
  if(has2){ xv2 = *(const float4*)(xb + r2*Hc + c2*4);
            pv2 = *(const float4*)(pe + r2*Hc + c2*4); }

  for(int kt = 0; kt < 16; ++kt){
    __syncthreads();
    tile[r1*16 + (c1 ^ (r1&7))] = make_float4(xv1.x+pv1.x, xv1.y+pv1.y, xv1.z+pv1.z, xv1.w+pv1.w);
    if(has2)
      tile[r2*16 + (c2 ^ (r2&7))] = make_float4(xv2.x+pv2.x, xv2.y+pv2.y, xv2.z+pv2.z, xv2.w+pv2.w);
    if(kt < 15){
      int ko = (kt+1)*64;
      xv1 = *(const float4*)(xb + r1*Hc + ko + c1*4);
      pv1 = *(const float4*)(pe + r1*Hc + ko + c1*4);
      if(has2){ xv2 = *(const float4*)(xb + r2*Hc + ko + c2*4);
                pv2 = *(const float4*)(pe + r2*Hc + ko + c2*4); }
    }
    __syncthreads();
    #pragma unroll
    for(int j = 0; j < 2; ++j){
      float4 xe = tile[r*16 + ((kq*2 + j) ^ (r&7))];
      const float* vk = vb + kt*64 + kq*8 + j*4;
      #pragma unroll
      for(int n = 0; n < Nc; ++n){
        const float* vn = vk + n*Hc;
        acc[n] = fmaf(xe.x, vn[0], acc[n]);
        acc[n] = fmaf(xe.y, vn[1], acc[n]);
        acc[n] = fmaf(xe.z, vn[2], acc[n]);
        acc[n] = fmaf(xe.w, vn[3], acc[n]);
      }
    }
  }
  if(valid){
    #pragma unroll
    for(int n = 0; n < Nc; ++n) part[kq][n][rw] = acc[n];
  }
  __syncthreads();

  if(w < Nc){
    int n = w, j = lane;
    float best = -FLT_MAX; int bidx = 0;
    #pragma unroll
    for(int i = 0; i < 2; ++i){
      int s2 = j + 64*i;
      if(s2 < Sc){
        float dot = 0.f;
        #pragma unroll
        for(int q = 0; q < 8; ++q) dot += part[q][n][s2];
        float y = dot/3200.0f + g[(size_t)(b*Nc + n)*Sc + s2];
        if(y > best){ best = y; bidx = s2; }   // strict > keeps first index (jnp tie rule)
      }
    }
    #pragma unroll
    for(int m = 32; m >= 1; m >>= 1){
      float ob = __shfl_xor(best, m, 64);
      int   oi = __shfl_xor(bidx, m, 64);
      if(ob > best || (ob == best && oi < bidx)){ best = ob; bidx = oi; }
    }
    if(j == 0) sidx[n] = bidx;
  }
  __syncthreads();

  const float4* xb4 = (const float4*)xb;
  float4* ob4 = (float4*)(out + (size_t)b*Nc*Hc);
  #pragma unroll
  for(int i = 0; i < 2; ++i){
    int idx = i*1024 + t;
    int nn = idx >> 8, c = idx & 255;
    ob4[idx] = xb4[sidx[nn]*256 + c];
  }
}

extern "C" void kernel_launch(void* const* d_in, const int* in_sizes, int n_in,
                              void* d_out, int out_size, void* d_ws, size_t ws_size,
                              hipStream_t stream) {
  const float* x  = (const float*)d_in[0];   // [512,100,1024]
  const float* Wq = (const float*)d_in[1];   // [1024,1024]
  const float* Wk = (const float*)d_in[2];   // [1024,1024]
  const float* g  = (const float*)d_in[3];   // [4096,100]
  float* out = (float*)d_out;                // [512,8,1024]

  char* ws = (char*)d_ws;
  // liveness-based aliasing (round-9 proven): v overwrites xsp/xs/low-Ksum8 (dead by v_gemm4).
  float* pe    = (float*)(ws);                //    409,600 B
  float* pesum = (float*)(ws +    409600);    //      4,096 B
  float* xsp   = (float*)(ws +    413696);    //  8,388,608 B  [512][4][1024]
  float* xs    = (float*)(ws +   8802304);    //  2,097,152 B  [512][1024]
  float* Ksum8 = (float*)(ws +  10899456);    // 16,777,216 B  [8][512][1024]
  float* Ksum  = (float*)(ws +  27676672);    //  2,097,152 B  [512][1024]
  float* v     = (float*)(ws +    413696);    // 16,777,216 B  alias (ends 17,190,912; Ksum8 dead)
                                              // total 29,773,824 B (proven size)

  pe_kernel    <<<100, 256, 0, stream>>>(pe);
  pesum_kernel <<<4,   256, 0, stream>>>(pe, pesum);
  xsum_kernel  <<<dim3(512,4), 256, 0, stream>>>(x, pesum, xsp);
  xsred_kernel <<<512, 256, 0, stream>>>(xsp, xs);
  ksum_gemm4   <<<dim3(8,4,8), 256, 0, stream>>>(xs, Wk, Ksum8);
  ksred8_kernel<<<512, 256, 0, stream>>>(Ksum8, Ksum);
  v_gemm4      <<<dim3(8,4,8), 256, 0, stream>>>(Ksum, Wq, v);
  attn_kernel  <<<512, 1024, 0, stream>>>(x, pe, v, g, out);
}

// Round 13
// 144.068 us; speedup vs baseline: 2.0905x; 1.0091x over previous
//
#include <hip/hip_runtime.h>
#include <float.h>
#include <math.h>

#define Bc 512
#define Sc 100
#define Hc 1024
#define Ac 128
#define Nc 8
#define PDST 196   // [k][*] tile row stride: 16 blocks x (8 data + 4 pad) + 4

// ---------------- K0a: positional-encoding table pe[S][H] ----------------
__global__ __launch_bounds__(256) void pe_kernel(float* __restrict__ pe){
  int s = blockIdx.x;
  int t = threadIdx.x;
  const float fac = (float)(-9.210340371976184 / 1024.0);  // -ln(10000)/H
  for(int i = t; i < Hc/2; i += 256){
    float div = expf((float)(2*i) * fac);
    float a = (float)s * div;
    pe[s*Hc + 2*i]     = sinf(a);
    pe[s*Hc + 2*i + 1] = cosf(a);
  }
}

// ---------------- K0b: pesum[h] = sum_s pe[s][h] ----------------
__global__ __launch_bounds__(256) void pesum_kernel(const float* __restrict__ pe, float* __restrict__ pesum){
  int h = blockIdx.x*256 + threadIdx.x;
  float acc = 0.f;
  for(int s = 0; s < Sc; ++s) acc += pe[s*Hc + h];
  pesum[h] = acc;
}

// ---------------- K1: xsp[b][q][h] = sum_{s in quarter q} x[b,s,h]  (+pesum at q==0) ----------------
__global__ __launch_bounds__(256) void xsum_kernel(const float* __restrict__ x, const float* __restrict__ pesum,
                                                   float* __restrict__ xsp){
  int b = blockIdx.x;
  int q = blockIdx.y;
  int t = threadIdx.x;
  const float4* xr = (const float4*)(x + (size_t)b*Sc*Hc);
  float4 acc;
  if(q == 0) acc = ((const float4*)pesum)[t];
  else       acc = make_float4(0.f,0.f,0.f,0.f);
  int s0 = q*25;
  #pragma unroll 5
  for(int s = s0; s < s0+25; ++s){
    float4 v = xr[s*(Hc/4) + t];
    acc.x += v.x; acc.y += v.y; acc.z += v.z; acc.w += v.w;
  }
  ((float4*)(xsp + ((size_t)b*4 + q)*Hc))[t] = acc;
}

// ---------------- K1b: xs[b][h] = sum_q xsp[b][q][h] ----------------
__global__ __launch_bounds__(256) void xsred_kernel(const float* __restrict__ xsp, float* __restrict__ xs){
  int b = blockIdx.x, t = threadIdx.x;
  const float4* p = (const float4*)(xsp + (size_t)b*4*Hc);
  float4 a = p[t], b1 = p[256+t], c = p[512+t], d = p[768+t];
  a.x += b1.x + c.x + d.x;
  a.y += b1.y + c.y + d.y;
  a.z += b1.z + c.z + d.z;
  a.w += b1.w + c.w + d.w;
  ((float4*)(xs + (size_t)b*Hc))[t] = a;
}

// ---------------- K2: Ksum8[ks][b][j] = sum_{k in slice ks(128)} xs[b][k] * Wk[j][k] ----------------
// 128x128 tile, 8x8 fragment (round-12 proven).
__global__ __launch_bounds__(256) void ksum_gemm4(const float* __restrict__ xs, const float* __restrict__ Wk,
                                                  float* __restrict__ Ksum8){
  __shared__ float As[32*PDST];
  __shared__ float Bs[32*PDST];
  const int t = threadIdx.x;
  const int j0 = blockIdx.x*128, b0 = blockIdx.y*128, kb = blockIdx.z*128;
  const int ty = t>>4, tx = t&15;
  const int lr = t>>1, lh = t&1;
  const int pj = (lr>>3)*12 + (lr&7);

  float acc[8][8];
  #pragma unroll
  for(int i = 0; i < 8; ++i)
    #pragma unroll
    for(int j = 0; j < 8; ++j) acc[i][j] = 0.f;

  const float* xa = xs + (size_t)(b0+lr)*Hc + kb + lh*16;
  const float* wa = Wk + (size_t)(j0+lr)*Hc + kb + lh*16;
  float4 a4[4], b4[4], a4n[4], b4n[4];
  #pragma unroll
  for(int i = 0; i < 4; ++i){ a4[i] = *(const float4*)(xa + i*4);
                              b4[i] = *(const float4*)(wa + i*4); }

  for(int c0 = 0; c0 < 4; ++c0){
    __syncthreads();
    #pragma unroll
    for(int i = 0; i < 4; ++i){
      int k = lh*16 + i*4;
      As[(k+0)*PDST + pj] = a4[i].x; As[(k+1)*PDST + pj] = a4[i].y;
      As[(k+2)*PDST + pj] = a4[i].z; As[(k+3)*PDST + pj] = a4[i].w;
      Bs[(k+0)*PDST + pj] = b4[i].x; Bs[(k+1)*PDST + pj] = b4[i].y;
      Bs[(k+2)*PDST + pj] = b4[i].z; Bs[(k+3)*PDST + pj] = b4[i].w;
    }
    if(c0 < 3){
      #pragma unroll
      for(int i = 0; i < 4; ++i){
        a4n[i] = *(const float4*)(xa + (c0+1)*32 + i*4);
        b4n[i] = *(const float4*)(wa + (c0+1)*32 + i*4);
      }
    }
    __syncthreads();
    #pragma unroll 4
    for(int kk = 0; kk < 32; ++kk){
      const float* ar = &As[kk*PDST + ty*12];
      const float* br = &Bs[kk*PDST + tx*12];
      float4 au = *(const float4*)(ar),   av = *(const float4*)(ar + 4);
      float4 bu = *(const float4*)(br),   bv = *(const float4*)(br + 4);
      float am[8] = {au.x,au.y,au.z,au.w, av.x,av.y,av.z,av.w};
      float bn[8] = {bu.x,bu.y,bu.z,bu.w, bv.x,bv.y,bv.z,bv.w};
      #pragma unroll
      for(int i = 0; i < 8; ++i)
        #pragma unroll
        for(int j = 0; j < 8; ++j)
          acc[i][j] = fmaf(am[i], bn[j], acc[i][j]);
    }
    a4[0]=a4n[0]; a4[1]=a4n[1]; a4[2]=a4n[2]; a4[3]=a4n[3];
    b4[0]=b4n[0]; b4[1]=b4n[1]; b4[2]=b4n[2]; b4[3]=b4n[3];
  }

  #pragma unroll
  for(int i = 0; i < 8; ++i){
    float* cp = Ksum8 + (((size_t)blockIdx.z*Bc + b0 + ty*8 + i)<<10) + j0 + tx*8;
    *(float4*)cp     = make_float4(acc[i][0],acc[i][1],acc[i][2],acc[i][3]);
    *(float4*)(cp+4) = make_float4(acc[i][4],acc[i][5],acc[i][6],acc[i][7]);
  }
}

// ---------------- K2b: Ksum[b][j] = sum_ks Ksum8[ks][b][j] ----------------
__global__ __launch_bounds__(256) void ksred8_kernel(const float* __restrict__ Ksum8, float* __restrict__ Ksum){
  int b = blockIdx.x, t = threadIdx.x;
  const float4* p = (const float4*)(Ksum8 + ((size_t)b<<10));
  const size_t sl = (size_t)Bc*Hc/4;
  float4 a = p[t];
  #pragma unroll
  for(int i = 1; i < 8; ++i){
    float4 q = p[i*sl + t];
    a.x += q.x; a.y += q.y; a.z += q.z; a.w += q.w;
  }
  ((float4*)(Ksum + ((size_t)b<<10)))[t] = a;
}

// ---------------- K3: v[b][n][h] = sum_a Ksum[b][n*A+a] * Wq[n*A+a][h] ----------------
__global__ __launch_bounds__(256) void v_gemm4(const float* __restrict__ Ksum, const float* __restrict__ Wq,
                                               float* __restrict__ v){
  __shared__ float As[32*PDST];
  __shared__ float Bs[32*PDST];
  const int t = threadIdx.x;
  const int h0 = blockIdx.x*128, b0 = blockIdx.y*128, n = blockIdx.z;
  const int ty = t>>4, tx = t&15;
  const int lr = t>>1, lh = t&1;
  const int pj = (lr>>3)*12 + (lr&7);
  const int rr = t>>3, cc = t&7;

  float acc[8][8];
  #pragma unroll
  for(int i = 0; i < 8; ++i)
    #pragma unroll
    for(int j = 0; j < 8; ++j) acc[i][j] = 0.f;

  const float* ka = Ksum + (size_t)(b0+lr)*Hc + n*Ac + lh*16;
  float4 a4[4], b4[4], a4n[4], b4n[4];
  #pragma unroll
  for(int i = 0; i < 4; ++i){
    a4[i] = *(const float4*)(ka + i*4);
    b4[i] = *(const float4*)(Wq + (size_t)(n*Ac + rr)*Hc + h0 + cc*16 + i*4);
  }

  for(int c0 = 0; c0 < 4; ++c0){
    __syncthreads();
    #pragma unroll
    for(int i = 0; i < 4; ++i){
      int k = lh*16 + i*4;
      As[(k+0)*PDST + pj] = a4[i].x; As[(k+1)*PDST + pj] = a4[i].y;
      As[(k+2)*PDST + pj] = a4[i].z; As[(k+3)*PDST + pj] = a4[i].w;
      int h = cc*16 + i*4;
      *(float4*)&Bs[rr*PDST + (h>>3)*12 + (h&7)] = b4[i];
    }
    if(c0 < 3){
      #pragma unroll
      for(int i = 0; i < 4; ++i){
        a4n[i] = *(const float4*)(ka + (c0+1)*32 + i*4);
        b4n[i] = *(const float4*)(Wq + (size_t)(n*Ac + (c0+1)*32 + rr)*Hc + h0 + cc*16 + i*4);
      }
    }
    __syncthreads();
    #pragma unroll 4
    for(int kk = 0; kk < 32; ++kk){
      const float* ar = &As[kk*PDST + ty*12];
      const float* br = &Bs[kk*PDST + tx*12];
      float4 au = *(const float4*)(ar),   av = *(const float4*)(ar + 4);
      float4 bu = *(const float4*)(br),   bv = *(const float4*)(br + 4);
      float am[8] = {au.x,au.y,au.z,au.w, av.x,av.y,av.z,av.w};
      float bn[8] = {bu.x,bu.y,bu.z,bu.w, bv.x,bv.y,bv.z,bv.w};
      #pragma unroll
      for(int i = 0; i < 8; ++i)
        #pragma unroll
        for(int j = 0; j < 8; ++j)
          acc[i][j] = fmaf(am[i], bn[j], acc[i][j]);
    }
    a4[0]=a4n[0]; a4[1]=a4n[1]; a4[2]=a4n[2]; a4[3]=a4n[3];
    b4[0]=b4n[0]; b4[1]=b4n[1]; b4[2]=b4n[2]; b4[3]=b4n[3];
  }

  #pragma unroll
  for(int i = 0; i < 8; ++i){
    float* cp = v + (((size_t)(b0 + ty*8 + i)*Nc + n)<<10) + h0 + tx*8;
    *(float4*)cp     = make_float4(acc[i][0],acc[i][1],acc[i][2],acc[i][3]);
    *(float4*)(cp+4) = make_float4(acc[i][4],acc[i][5],acc[i][6],acc[i][7]);
  }
}

// ---------------- K4: x.v logits -> +gumbel -> argmax_s -> gather rows of x ----------------
// 512 thr = 8 waves, wave = k-eighth, lane owns TWO s-rows (lane, lane+64):
// each v broadcast load now feeds 16 FMAs (2 rows x 8 comps) -> v VMEM-issue halved
// vs round-4 structure. Same XOR-swizzled x-tile staging, 2 blocks/CU.
__global__ __launch_bounds__(512) void attn_kernel(const float* __restrict__ x, const float* __restrict__ pe,
                                                   const float* __restrict__ v, const float* __restrict__ g,
                                                   float* __restrict__ out){
  __shared__ float4 tile[1600];        // [r<100][16 slots], 16B-slot XOR swizzle, 25.6 KB
  __shared__ float part[8][Nc][104];   // [kq][n][s] 26.6 KB
  __shared__ int sidx[Nc];
  const int b = blockIdx.x;
  const int t = threadIdx.x;
  const int lane = t & 63;
  const int kq = __builtin_amdgcn_readfirstlane(t >> 6);  // wave id 0..7 = k-eighth

  // staging roles: elements {t, t+512, t+1024, t+1536 (t<64)} of 1600 float4s
  const int rA = t >> 4,          cA = t & 15;
  const int rB = (t+512) >> 4,    cB = (t+512) & 15;
  const int rC = (t+1024) >> 4,   cC = (t+1024) & 15;
  const bool hasD = (t < 64);
  const int rD = (t+1536) >> 4,   cD = (t+1536) & 15;

  const float* xb = x + (size_t)b*Sc*Hc;
  const float* vb = v + (size_t)b*Nc*Hc;

  const int r0 = lane;                 // row 0..63 (always valid)
  const int r1v = lane + 64;           // 64..127; >=100 dummy
  const int r1 = (r1v < Sc) ? r1v : (Sc-1);
  const bool val1 = (r1v < Sc);

  float acc0[Nc], acc1[Nc];
  #pragma unroll
  for(int n = 0; n < Nc; ++n){ acc0[n] = 0.f; acc1[n] = 0.f; }

  // prologue: tile-0 loads into regs
  float4 xvA = *(const float4*)(xb + rA*Hc + cA*4);
  float4 pvA = *(const float4*)(pe + rA*Hc + cA*4);
  float4 xvB = *(const float4*)(xb + rB*Hc + cB*4);
  float4 pvB = *(const float4*)(pe + rB*Hc + cB*4);
  float4 xvC = *(const float4*)(xb + rC*Hc + cC*4);
  float4 pvC = *(const float4*)(pe + rC*Hc + cC*4);
  float4 xvD = make_float4(0,0,0,0), pvD = make_float4(0,0,0,0);
  if(hasD){ xvD = *(const float4*)(xb + rD*Hc + cD*4);
            pvD = *(const float4*)(pe + rD*Hc + cD*4); }

  for(int kt = 0; kt < 16; ++kt){
    __syncthreads();                   // previous tile's reads complete
    tile[rA*16 + (cA ^ (rA&7))] = make_float4(xvA.x+pvA.x, xvA.y+pvA.y, xvA.z+pvA.z, xvA.w+pvA.w);
    tile[rB*16 + (cB ^ (rB&7))] = make_float4(xvB.x+pvB.x, xvB.y+pvB.y, xvB.z+pvB.z, xvB.w+pvB.w);
    tile[rC*16 + (cC ^ (rC&7))] = make_float4(xvC.x+pvC.x, xvC.y+pvC.y, xvC.z+pvC.z, xvC.w+pvC.w);
    if(hasD)
      tile[rD*16 + (cD ^ (rD&7))] = make_float4(xvD.x+pvD.x, xvD.y+pvD.y, xvD.z+pvD.z, xvD.w+pvD.w);
    if(kt < 15){                       // prefetch next tile
      int ko = (kt+1)*64;
      xvA = *(const float4*)(xb + rA*Hc + ko + cA*4);
      pvA = *(const float4*)(pe + rA*Hc + ko + cA*4);
      xvB = *(const float4*)(xb + rB*Hc + ko + cB*4);
      pvB = *(const float4*)(pe + rB*Hc + ko + cB*4);
      xvC = *(const float4*)(xb + rC*Hc + ko + cC*4);
      pvC = *(const float4*)(pe + rC*Hc + ko + cC*4);
      if(hasD){ xvD = *(const float4*)(xb + rD*Hc + ko + cD*4);
                pvD = *(const float4*)(pe + rD*Hc + ko + cD*4); }
    }
    __syncthreads();                   // tile staged
    #pragma unroll
    for(int j = 0; j < 2; ++j){
      float4 xe0 = tile[r0*16 + ((kq*2 + j) ^ (r0&7))];
      float4 xe1 = tile[r1*16 + ((kq*2 + j) ^ (r1&7))];
      const float* vk = vb + kt*64 + kq*8 + j*4;
      #pragma unroll
      for(int n = 0; n < Nc; ++n){
        float4 vv = *(const float4*)(vk + n*Hc);   // one broadcast load -> 16 FMA
        acc0[n] = fmaf(xe0.x, vv.x, acc0[n]);
        acc0[n] = fmaf(xe0.y, vv.y, acc0[n]);
        acc0[n] = fmaf(xe0.z, vv.z, acc0[n]);
        acc0[n] = fmaf(xe0.w, vv.w, acc0[n]);
        acc1[n] = fmaf(xe1.x, vv.x, acc1[n]);
        acc1[n] = fmaf(xe1.y, vv.y, acc1[n]);
        acc1[n] = fmaf(xe1.z, vv.z, acc1[n]);
        acc1[n] = fmaf(xe1.w, vv.w, acc1[n]);
      }
    }
  }
  #pragma unroll
  for(int n = 0; n < Nc; ++n){
    part[kq][n][r0] = acc0[n];
    if(val1) part[kq][n][r1v] = acc1[n];
  }
  __syncthreads();

  // phase 2: y = dot/3200 + gumbel; argmax over s. Wave kq handles head n=kq.
  {
    int n = kq, j = lane;
    float best = -FLT_MAX; int bidx = 0;
    #pragma unroll
    for(int i = 0; i < 2; ++i){
      int s2 = j + 64*i;
      if(s2 < Sc){
        float dot = 0.f;
        #pragma unroll
        for(int q = 0; q < 8; ++q) dot += part[q][n][s2];
        float y = dot/3200.0f + g[(size_t)(b*Nc + n)*Sc + s2];
        if(y > best){ best = y; bidx = s2; }   // strict > keeps first index (jnp tie rule)
      }
    }
    #pragma unroll
    for(int m = 32; m >= 1; m >>= 1){
      float ob = __shfl_xor(best, m, 64);
      int   oi = __shfl_xor(bidx, m, 64);
      if(ob > best || (ob == best && oi < bidx)){ best = ob; bidx = oi; }
    }
    if(j == 0) sidx[n] = bidx;
  }
  __syncthreads();

  // phase 3: out[b,n,:] = x[b, s*, :]  (2048 float4 over 512 threads)
  const float4* xb4 = (const float4*)xb;
  float4* ob4 = (float4*)(out + (size_t)b*Nc*Hc);
  #pragma unroll
  for(int i = 0; i < 4; ++i){
    int idx = i*512 + t;
    int nn = idx >> 8, c = idx & 255;
    ob4[idx] = xb4[sidx[nn]*256 + c];
  }
}

extern "C" void kernel_launch(void* const* d_in, const int* in_sizes, int n_in,
                              void* d_out, int out_size, void* d_ws, size_t ws_size,
                              hipStream_t stream) {
  const float* x  = (const float*)d_in[0];   // [512,100,1024]
  const float* Wq = (const float*)d_in[1];   // [1024,1024]
  const float* Wk = (const float*)d_in[2];   // [1024,1024]
  const float* g  = (const float*)d_in[3];   // [4096,100]
  float* out = (float*)d_out;                // [512,8,1024]

  char* ws = (char*)d_ws;
  // liveness-based aliasing (round-9 proven): v overwrites xsp/xs/low-Ksum8 (dead by v_gemm4).
  float* pe    = (float*)(ws);                //    409,600 B
  float* pesum = (float*)(ws +    409600);    //      4,096 B
  float* xsp   = (float*)(ws +    413696);    //  8,388,608 B  [512][4][1024]
  float* xs    = (float*)(ws +   8802304);    //  2,097,152 B  [512][1024]
  float* Ksum8 = (float*)(ws +  10899456);    // 16,777,216 B  [8][512][1024]
  float* Ksum  = (float*)(ws +  27676672);    //  2,097,152 B  [512][1024]
  float* v     = (float*)(ws +    413696);    // 16,777,216 B  alias (ends 17,190,912; Ksum8 dead)
                                              // total 29,773,824 B (proven size)

  pe_kernel    <<<100, 256, 0, stream>>>(pe);
  pesum_kernel <<<4,   256, 0, stream>>>(pe, pesum);
  xsum_kernel  <<<dim3(512,4), 256, 0, stream>>>(x, pesum, xsp);
  xsred_kernel <<<512, 256, 0, stream>>>(xsp, xs);
  ksum_gemm4   <<<dim3(8,4,8), 256, 0, stream>>>(xs, Wk, Ksum8);
  ksred8_kernel<<<512, 256, 0, stream>>>(Ksum8, Ksum);
  v_gemm4      <<<dim3(8,4,8), 256, 0, stream>>>(Ksum, Wq, v);
  attn_kernel  <<<512, 512, 0, stream>>>(x, pe, v, g, out);
}